// Round 5
// baseline (1758.620 us; speedup 1.0000x reference)
//
#include <hip/hip_runtime.h>

#define B_    64
#define C_    512
#define H_    32
#define WDIM  32
#define N_    1024   // H*W
#define M3C   1536   // 3*C

typedef unsigned short ushort_t;
typedef __attribute__((ext_vector_type(8))) short bf16x8;
typedef __attribute__((ext_vector_type(4))) float f32x4;

#define MEMFENCE asm volatile("" ::: "memory")

// ---------------------------------------------------------------------------
// bf16 split helpers (RNE)
// ---------------------------------------------------------------------------
__device__ __forceinline__ ushort_t f2bf(float x) {
    unsigned u = __float_as_uint(x);
    unsigned r = (u + 0x7FFFu + ((u >> 16) & 1u)) >> 16;
    return (ushort_t)r;
}
__device__ __forceinline__ float bf2f(ushort_t b) {
    return __uint_as_float(((unsigned)b) << 16);
}
__device__ __forceinline__ void split_write(float v, ushort_t* __restrict__ ph,
                                            ushort_t* __restrict__ pl, size_t idx) {
    ushort_t hb = f2bf(v);
    ph[idx] = hb;
    pl[idx] = f2bf(v - bf2f(hb));
}

// async global->LDS, 16B per lane (dst = wave-uniform base + lane*16)
__device__ __forceinline__ void gld16(const void* g, void* l) {
    __builtin_amdgcn_global_load_lds((const __attribute__((address_space(1))) unsigned int*)g,
                                     (__attribute__((address_space(3))) unsigned int*)l,
                                     16, 0, 0);
}

// ---------------------------------------------------------------------------
// pos[c, h*W+w] = rel_h[c,h] + rel_w[c,w]   (fp32)
// ---------------------------------------------------------------------------
__global__ __launch_bounds__(256) void pos_kernel(const float* __restrict__ rel_h,
                                                  const float* __restrict__ rel_w,
                                                  float* __restrict__ pos) {
    int idx = blockIdx.x * 256 + threadIdx.x;
    if (idx >= C_ * N_) return;
    int c = idx >> 10;
    int n = idx & (N_ - 1);
    int h = n >> 5;
    int w = n & (WDIM - 1);
    pos[idx] = rel_h[c * H_ + h] + rel_w[c * WDIM + w];
}

// ---------------------------------------------------------------------------
// fp32 GEMM, both operands k-major: D[m][n] = sum_k A[k][m] * B[k][n]
// (used once for M = Wq^T Wk and r = Wq^T pos; tiny)
// ---------------------------------------------------------------------------
__global__ __launch_bounds__(256) void mmT_f32(const float* __restrict__ A, int lda,
                                               const float* __restrict__ B, int ldb,
                                               float* __restrict__ D, int ldd, int K) {
    __shared__ float As[16][64];
    __shared__ float Bs[16][64];
    const int m0 = blockIdx.y * 64;
    const int n0 = blockIdx.x * 64;
    const int tx = threadIdx.x, ty = threadIdx.y;
    const int tid = ty * 16 + tx;
    float acc[4][4] = {};
    for (int k0 = 0; k0 < K; k0 += 16) {
        #pragma unroll
        for (int t = 0; t < 4; ++t) {
            int e = tid + t * 256;
            int j = e >> 6, i = e & 63;
            As[j][i] = A[(size_t)(k0 + j) * lda + m0 + i];
            Bs[j][i] = B[(size_t)(k0 + j) * ldb + n0 + i];
        }
        __syncthreads();
        #pragma unroll
        for (int kk = 0; kk < 16; ++kk) {
            float a[4], bb[4];
            #pragma unroll
            for (int i = 0; i < 4; ++i) a[i]  = As[kk][ty * 4 + i];
            #pragma unroll
            for (int j = 0; j < 4; ++j) bb[j] = Bs[kk][tx * 4 + j];
            #pragma unroll
            for (int i = 0; i < 4; ++i)
                #pragma unroll
                for (int j = 0; j < 4; ++j)
                    acc[i][j] += a[i] * bb[j];
        }
        __syncthreads();
    }
    #pragma unroll
    for (int i = 0; i < 4; ++i)
        #pragma unroll
        for (int j = 0; j < 4; ++j)
            D[(size_t)(m0 + ty * 4 + i) * ldd + n0 + tx * 4 + j] = acc[i][j];
}

// ---------------------------------------------------------------------------
// F = [M ; Wv] split into bf16 hi/lo planes, natural [o][c] layout (k=c inner)
// ---------------------------------------------------------------------------
__global__ __launch_bounds__(256) void f_split(const float* __restrict__ Mtmp,
                                               const float* __restrict__ Wm,
                                               ushort_t* __restrict__ Fh,
                                               ushort_t* __restrict__ Fl) {
    int idx = blockIdx.x * 256 + threadIdx.x;
    if (idx >= 1024 * C_) return;
    int o = idx >> 9;
    int c = idx & (C_ - 1);
    float v = (o < 512) ? Mtmp[idx] : Wm[(size_t)(512 + o) * C_ + c];
    split_write(v, Fh, Fl, idx);
}

// ---------------------------------------------------------------------------
// transpose+split: src[C_][N_] fp32 -> dst hi/lo planes [N_][C_] bf16
// ---------------------------------------------------------------------------
__global__ __launch_bounds__(256) void xT_split(const float* __restrict__ x,
                                                ushort_t* __restrict__ xh,
                                                ushort_t* __restrict__ xl) {
    __shared__ float t[32][33];
    const int bl = blockIdx.z;
    const int c0 = blockIdx.y * 32;
    const int n0 = blockIdx.x * 32;
    const float* xb = x + (size_t)bl * C_ * N_;
    ushort_t* xhb = xh + (size_t)bl * N_ * C_;
    ushort_t* xlb = xl + (size_t)bl * N_ * C_;
    const int tx = threadIdx.x & 31, ty = threadIdx.x >> 5;
    #pragma unroll
    for (int r = 0; r < 4; ++r)
        t[ty + r * 8][tx] = xb[(size_t)(c0 + ty + r * 8) * N_ + n0 + tx];
    __syncthreads();
    #pragma unroll
    for (int r = 0; r < 4; ++r) {
        float v = t[tx][ty + r * 8];
        size_t o = (size_t)(n0 + ty + r * 8) * C_ + c0 + tx;
        split_write(v, xhb, xlb, o);
    }
}

// ===========================================================================
// Quadrant-phased 256x256 GEMM, 8 waves (2x4), BK=64, 16x16x32 MFMA.
// LDS: A[2buf][2half][128x64], B[2buf][2half][128x64] bf16 = 128 KiB.
// Swizzle: 16B chunk' = chunk ^ (row&7) within each 128B row (8 chunks);
//   staged via global_load_lds with pre-swizzled per-lane SOURCE (linear
//   LDS dest); read side applies the same XOR.  Lanes 0-7 of every
//   ds_read_b128 cover all 32 banks exactly once (conflict-free).
// Schedule: tile t = 4 phases, phase q computes C-quadrant (q>>1, q&1):
//   per phase: [vmcnt(8); s_barrier; issue 1 half-tile (2 gld16);
//   12 ds_read_b128; lgkmcnt(0)+sched_barrier; setprio(1) 16 MFMA setprio(0)]
// Half queue order per tile: A0,B0,B1,A1; half h issued at phase h+... 6
// slots ahead (prologue stages 6 halves).  Accounting (exact):
//   deadline(A0,B0)=4t, (B1)=4t+1, (A1)=4t+2; issue(A0)=4t-6,(B0)=4t-5,
//   (B1)=4t-4,(A1)=4t-3; vmcnt(8) completes every half <= phase+1;
//   issue slot = prev occupant's last-read phase + 1 (after the barrier).
// Final tile: graduated vmcnt(4/2/0).
// ===========================================================================

#define STAGE2(srcp, gstride, r0, kb, dstp) \
    _Pragma("unroll") \
    for (int s_ = 0; s_ < 2; ++s_) { \
        int row_ = s_ * 64 + (tid >> 3); \
        gld16((srcp) + (size_t)((r0) + row_) * (gstride) + (kb) + \
                  (((tid & 7) ^ (row_ & 7)) << 4), \
              (dstp) + s_ * 4096 + (wid << 9)); \
    }

#define PHASE_WAIT(t_, q_, TT) \
    if ((t_) < (TT) - 1) asm volatile("s_waitcnt vmcnt(8)" ::: "memory"); \
    else if ((q_) == 0)  asm volatile("s_waitcnt vmcnt(4)" ::: "memory"); \
    else if ((q_) == 1)  asm volatile("s_waitcnt vmcnt(2)" ::: "memory"); \
    else                 asm volatile("s_waitcnt vmcnt(0)" ::: "memory");

#define PHASE_COMPUTE(buf_, qr_, qc_, q_) \
    bf16x8 af_[4][2], bf_[2][2]; \
    _Pragma("unroll") \
    for (int i_ = 0; i_ < 4; ++i_) { \
        int row_ = wr * 64 + i_ * 16 + lr; \
        const ushort_t* ab_ = &ldsA[buf_][qr_][row_ * 64]; \
        af_[i_][0] = *(const bf16x8*)&ab_[((g ^ (row_ & 7)) << 3)]; \
        af_[i_][1] = *(const bf16x8*)&ab_[(((4 + g) ^ (row_ & 7)) << 3)]; \
    } \
    _Pragma("unroll") \
    for (int j_ = 0; j_ < 2; ++j_) { \
        int row_ = wc * 32 + j_ * 16 + lr; \
        const ushort_t* bb_ = &ldsB[buf_][qc_][row_ * 64]; \
        bf_[j_][0] = *(const bf16x8*)&bb_[((g ^ (row_ & 7)) << 3)]; \
        bf_[j_][1] = *(const bf16x8*)&bb_[(((4 + g) ^ (row_ & 7)) << 3)]; \
    } \
    asm volatile("s_waitcnt lgkmcnt(0)" ::: "memory"); \
    __builtin_amdgcn_sched_barrier(0); \
    __builtin_amdgcn_s_setprio(1); \
    _Pragma("unroll") \
    for (int i_ = 0; i_ < 4; ++i_) \
        _Pragma("unroll") \
        for (int j_ = 0; j_ < 2; ++j_) { \
            acc[q_][i_][j_] = __builtin_amdgcn_mfma_f32_16x16x32_bf16(af_[i_][0], bf_[j_][0], acc[q_][i_][j_], 0, 0, 0); \
            acc[q_][i_][j_] = __builtin_amdgcn_mfma_f32_16x16x32_bf16(af_[i_][1], bf_[j_][1], acc[q_][i_][j_], 0, 0, 0); \
        } \
    __builtin_amdgcn_s_setprio(0);

// ---------------------------------------------------------------------------
// G1: y[o][n] = sum_c F[o][c] x[c][n]; logical K = 3*512 (Fh*xh, Fh*xl, Fl*xh)
//     o<512 -> tT[n][o] transposed+split;  o>=512 -> v[c][m] natural+split
// ---------------------------------------------------------------------------
__global__ __launch_bounds__(512, 2) void g1_mfma(const ushort_t* __restrict__ Fh_,
                                                  const ushort_t* __restrict__ Fl_,
                                                  const ushort_t* __restrict__ xTh_,
                                                  const ushort_t* __restrict__ xTl_,
                                                  ushort_t* __restrict__ tTh_,
                                                  ushort_t* __restrict__ tTl_,
                                                  ushort_t* __restrict__ vh_,
                                                  ushort_t* __restrict__ vl_) {
    __shared__ ushort_t ldsA[2][2][8192];
    __shared__ ushort_t ldsB[2][2][8192];
    const int bl = blockIdx.z;
    const int n0 = blockIdx.x * 256;
    const int m0 = blockIdx.y * 256;
    const char* fh = (const char*)Fh_;
    const char* fl = (const char*)Fl_;
    const char* xh = (const char*)(xTh_ + (size_t)bl * N_ * C_);
    const char* xl = (const char*)(xTl_ + (size_t)bl * N_ * C_);

    const int tid = threadIdx.x;
    const int lane = tid & 63, wid = tid >> 6;
    const int wr = wid >> 2, wc = wid & 3;
    const int lr = lane & 15, g = lane >> 4;
    const int T = 24;   // 3 segments x 8 k-tiles

    f32x4 acc[4][4][2] = {};

#define G1_STAGE(h_) do { \
    int th_ = (h_) >> 2, kind_ = (h_) & 3, bu_ = th_ & 1; \
    int seg_ = th_ >> 3, kb_ = (th_ & 7) * 128; \
    if (kind_ == 0 || kind_ == 3) { \
        int hf_ = (kind_ == 3); \
        const char* s_p = (seg_ == 2) ? fl : fh; \
        STAGE2(s_p, 1024, m0 + hf_ * 128, kb_, &ldsA[bu_][hf_][0]); \
    } else { \
        int hf_ = (kind_ == 2); \
        const char* s_p = (seg_ == 1) ? xl : xh; \
        STAGE2(s_p, 1024, n0 + hf_ * 128, kb_, &ldsB[bu_][hf_][0]); \
    } \
} while (0)

#define G1_PHASE(t_, q_, qr_, qc_) do { \
    PHASE_WAIT(t_, q_, T); \
    __builtin_amdgcn_s_barrier(); \
    MEMFENCE; \
    { int h_ = 4 * (t_) + (q_) + 6; if (h_ < 4 * T) G1_STAGE(h_); } \
    const int bu_ = (t_) & 1; \
    PHASE_COMPUTE(bu_, qr_, qc_, q_); \
} while (0)

    #pragma unroll
    for (int h = 0; h < 6; ++h) G1_STAGE(h);
    for (int t = 0; t < T; ++t) {
        G1_PHASE(t, 0, 0, 0);
        G1_PHASE(t, 1, 0, 1);
        G1_PHASE(t, 2, 1, 0);
        G1_PHASE(t, 3, 1, 1);
    }
#undef G1_PHASE
#undef G1_STAGE

    if (m0 < 512) {
        ushort_t* th = tTh_ + (size_t)bl * N_ * C_;
        ushort_t* tl = tTl_ + (size_t)bl * N_ * C_;
        #pragma unroll
        for (int q = 0; q < 4; ++q)
            #pragma unroll
            for (int i = 0; i < 4; ++i)
                #pragma unroll
                for (int j = 0; j < 2; ++j) {
                    int o = m0 + (q >> 1) * 128 + wr * 64 + i * 16 + g * 4;
                    int n = n0 + (q & 1) * 128 + wc * 32 + j * 16 + lr;
                    ushort4 h4, l4;
                    ushort_t hb;
                    float v0 = acc[q][i][j][0], v1 = acc[q][i][j][1];
                    float v2 = acc[q][i][j][2], v3 = acc[q][i][j][3];
                    hb = f2bf(v0); h4.x = hb; l4.x = f2bf(v0 - bf2f(hb));
                    hb = f2bf(v1); h4.y = hb; l4.y = f2bf(v1 - bf2f(hb));
                    hb = f2bf(v2); h4.z = hb; l4.z = f2bf(v2 - bf2f(hb));
                    hb = f2bf(v3); h4.w = hb; l4.w = f2bf(v3 - bf2f(hb));
                    *reinterpret_cast<ushort4*>(&th[(size_t)n * C_ + o]) = h4;
                    *reinterpret_cast<ushort4*>(&tl[(size_t)n * C_ + o]) = l4;
                }
    } else {
        ushort_t* vh = vh_ + (size_t)bl * C_ * N_;
        ushort_t* vl = vl_ + (size_t)bl * C_ * N_;
        #pragma unroll
        for (int q = 0; q < 4; ++q)
            #pragma unroll
            for (int i = 0; i < 4; ++i)
                #pragma unroll
                for (int j = 0; j < 2; ++j) {
                    int cb = m0 - 512 + (q >> 1) * 128 + wr * 64 + i * 16 + g * 4;
                    int m = n0 + (q & 1) * 128 + wc * 32 + j * 16 + lr;
                    #pragma unroll
                    for (int rr = 0; rr < 4; ++rr) {
                        float v = acc[q][i][j][rr];
                        ushort_t hb = f2bf(v);
                        vh[(size_t)(cb + rr) * N_ + m] = hb;
                        vl[(size_t)(cb + rr) * N_ + m] = f2bf(v - bf2f(hb));
                    }
                }
    }
}

// ---------------------------------------------------------------------------
// G2: S[n][m]; logical K = 6*512: {xh*th, xh*tl, xl*th, rh*xh, rh*xl, rl*xh}
// ---------------------------------------------------------------------------
__global__ __launch_bounds__(512, 2) void g2_mfma(const ushort_t* __restrict__ xTh_,
                                                  const ushort_t* __restrict__ xTl_,
                                                  const ushort_t* __restrict__ rTh_,
                                                  const ushort_t* __restrict__ rTl_,
                                                  const ushort_t* __restrict__ tTh_,
                                                  const ushort_t* __restrict__ tTl_,
                                                  float* __restrict__ S) {
    __shared__ ushort_t ldsA[2][2][8192];
    __shared__ ushort_t ldsB[2][2][8192];
    const int bl = blockIdx.z;
    const int m0 = blockIdx.x * 256;
    const int n0 = blockIdx.y * 256;
    const char* xh = (const char*)(xTh_ + (size_t)bl * N_ * C_);
    const char* xl = (const char*)(xTl_ + (size_t)bl * N_ * C_);
    const char* th = (const char*)(tTh_ + (size_t)bl * N_ * C_);
    const char* tl = (const char*)(tTl_ + (size_t)bl * N_ * C_);
    const char* rh = (const char*)rTh_;
    const char* rl = (const char*)rTl_;

    const int tid = threadIdx.x;
    const int lane = tid & 63, wid = tid >> 6;
    const int wr = wid >> 2, wc = wid & 3;
    const int lr = lane & 15, g = lane >> 4;
    const int T = 48;   // 6 segments x 8 k-tiles

    f32x4 acc[4][4][2] = {};

#define G2_STAGE(h_) do { \
    int th_ = (h_) >> 2, kind_ = (h_) & 3, bu_ = th_ & 1; \
    int seg_ = th_ >> 3, kb_ = (th_ & 7) * 128; \
    if (kind_ == 0 || kind_ == 3) { \
        int hf_ = (kind_ == 3); \
        const char* s_p = (seg_ < 3) ? ((seg_ == 2) ? xl : xh) \
                                     : ((seg_ == 5) ? rl : rh); \
        STAGE2(s_p, 1024, n0 + hf_ * 128, kb_, &ldsA[bu_][hf_][0]); \
    } else { \
        int hf_ = (kind_ == 2); \
        const char* s_p = (seg_ < 3) ? ((seg_ == 1) ? tl : th) \
                                     : ((seg_ == 4) ? xl : xh); \
        STAGE2(s_p, 1024, m0 + hf_ * 128, kb_, &ldsB[bu_][hf_][0]); \
    } \
} while (0)

#define G2_PHASE(t_, q_, qr_, qc_) do { \
    PHASE_WAIT(t_, q_, T); \
    __builtin_amdgcn_s_barrier(); \
    MEMFENCE; \
    { int h_ = 4 * (t_) + (q_) + 6; if (h_ < 4 * T) G2_STAGE(h_); } \
    const int bu_ = (t_) & 1; \
    PHASE_COMPUTE(bu_, qr_, qc_, q_); \
} while (0)

    #pragma unroll
    for (int h = 0; h < 6; ++h) G2_STAGE(h);
    for (int t = 0; t < T; ++t) {
        G2_PHASE(t, 0, 0, 0);
        G2_PHASE(t, 1, 0, 1);
        G2_PHASE(t, 2, 1, 0);
        G2_PHASE(t, 3, 1, 1);
    }
#undef G2_PHASE
#undef G2_STAGE

    float* Sb = S + (size_t)bl * N_ * N_;
    #pragma unroll
    for (int q = 0; q < 4; ++q)
        #pragma unroll
        for (int i = 0; i < 4; ++i)
            #pragma unroll
            for (int j = 0; j < 2; ++j) {
                int n = n0 + (q >> 1) * 128 + wr * 64 + i * 16 + g * 4;
                int m = m0 + (q & 1) * 128 + wc * 32 + j * 16 + lr;
                #pragma unroll
                for (int rr = 0; rr < 4; ++rr)
                    Sb[(size_t)(n + rr) * N_ + m] = acc[q][i][j][rr];
            }
}

// ---------------------------------------------------------------------------
// Row softmax (fp32 in) -> P bf16 [n][m]
// ---------------------------------------------------------------------------
__device__ __forceinline__ float waveMax(float v) {
    #pragma unroll
    for (int o = 32; o > 0; o >>= 1) v = fmaxf(v, __shfl_down(v, o));
    return v;
}
__device__ __forceinline__ float waveSum(float v) {
    #pragma unroll
    for (int o = 32; o > 0; o >>= 1) v += __shfl_down(v, o);
    return v;
}

__global__ __launch_bounds__(256) void softmax_bf16(const float* __restrict__ S,
                                                    ushort_t* __restrict__ P) {
    const float* Sr = S + (size_t)blockIdx.x * N_;
    ushort_t* Pr = P + (size_t)blockIdx.x * N_;
    const int tid = threadIdx.x;
    float4 v = reinterpret_cast<const float4*>(Sr)[tid];
    __shared__ float redm[4];
    __shared__ float reds[4];
    const int wave = tid >> 6, lane = tid & 63;

    float m = fmaxf(fmaxf(v.x, v.y), fmaxf(v.z, v.w));
    m = waveMax(m);
    if (lane == 0) redm[wave] = m;
    __syncthreads();
    m = fmaxf(fmaxf(redm[0], redm[1]), fmaxf(redm[2], redm[3]));

    v.x = __expf(v.x - m); v.y = __expf(v.y - m);
    v.z = __expf(v.z - m); v.w = __expf(v.w - m);
    float s = v.x + v.y + v.z + v.w;
    s = waveSum(s);
    if (lane == 0) reds[wave] = s;
    __syncthreads();
    s = reds[0] + reds[1] + reds[2] + reds[3];
    const float inv = 1.0f / s;
    ushort4 p;
    p.x = f2bf(v.x * inv); p.y = f2bf(v.y * inv);
    p.z = f2bf(v.z * inv); p.w = f2bf(v.w * inv);
    reinterpret_cast<ushort4*>(Pr)[tid] = p;
}

// ---------------------------------------------------------------------------
// G4: out[c][n] = sum_m v[c][m] P[n][m]; logical K = 2*1024: {vh*P, vl*P}
// ---------------------------------------------------------------------------
__global__ __launch_bounds__(512, 2) void g4_mfma(const ushort_t* __restrict__ vh_,
                                                  const ushort_t* __restrict__ vl_,
                                                  const ushort_t* __restrict__ P_,
                                                  float* __restrict__ out) {
    __shared__ ushort_t ldsA[2][2][8192];
    __shared__ ushort_t ldsB[2][2][8192];
    const int bl = blockIdx.z;
    const int n0 = blockIdx.x * 256;
    const int c0 = blockIdx.y * 256;
    const char* avh = (const char*)(vh_ + (size_t)bl * C_ * N_);
    const char* avl = (const char*)(vl_ + (size_t)bl * C_ * N_);
    const char* bp  = (const char*)(P_ + (size_t)bl * N_ * N_);

    const int tid = threadIdx.x;
    const int lane = tid & 63, wid = tid >> 6;
    const int wr = wid >> 2, wc = wid & 3;
    const int lr = lane & 15, g = lane >> 4;
    const int T = 32;   // 2 segments x 16 k-tiles

    f32x4 acc[4][4][2] = {};

#define G4_STAGE(h_) do { \
    int th_ = (h_) >> 2, kind_ = (h_) & 3, bu_ = th_ & 1; \
    int seg_ = th_ >> 4, kb_ = (th_ & 15) * 128; \
    if (kind_ == 0 || kind_ == 3) { \
        int hf_ = (kind_ == 3); \
        const char* s_p = seg_ ? avl : avh; \
        STAGE2(s_p, 2048, c0 + hf_ * 128, kb_, &ldsA[bu_][hf_][0]); \
    } else { \
        int hf_ = (kind_ == 2); \
        STAGE2(bp, 2048, n0 + hf_ * 128, kb_, &ldsB[bu_][hf_][0]); \
    } \
} while (0)

#define G4_PHASE(t_, q_, qr_, qc_) do { \
    PHASE_WAIT(t_, q_, T); \
    __builtin_amdgcn_s_barrier(); \
    MEMFENCE; \
    { int h_ = 4 * (t_) + (q_) + 6; if (h_ < 4 * T) G4_STAGE(h_); } \
    const int bu_ = (t_) & 1; \
    PHASE_COMPUTE(bu_, qr_, qc_, q_); \
} while (0)

    #pragma unroll
    for (int h = 0; h < 6; ++h) G4_STAGE(h);
    for (int t = 0; t < T; ++t) {
        G4_PHASE(t, 0, 0, 0);
        G4_PHASE(t, 1, 0, 1);
        G4_PHASE(t, 2, 1, 0);
        G4_PHASE(t, 3, 1, 1);
    }
#undef G4_PHASE
#undef G4_STAGE

    float* ob = out + (size_t)bl * C_ * N_;
    #pragma unroll
    for (int q = 0; q < 4; ++q)
        #pragma unroll
        for (int i = 0; i < 4; ++i)
            #pragma unroll
            for (int j = 0; j < 2; ++j) {
                int c = c0 + (q >> 1) * 128 + wr * 64 + i * 16 + g * 4;
                int n = n0 + (q & 1) * 128 + wc * 32 + j * 16 + lr;
                #pragma unroll
                for (int rr = 0; rr < 4; ++rr)
                    ob[(size_t)(c + rr) * N_ + n] = acc[q][i][j][rr];
            }
}

// ---------------------------------------------------------------------------
extern "C" void kernel_launch(void* const* d_in, const int* in_sizes, int n_in,
                              void* d_out, int out_size, void* d_ws, size_t ws_size,
                              hipStream_t stream) {
    const float* x     = (const float*)d_in[0];
    const float* Wm    = (const float*)d_in[1];
    const float* rel_h = (const float*)d_in[2];
    const float* rel_w = (const float*)d_in[3];
    float* out = (float*)d_out;

    const size_t posB  = (size_t)C_ * N_ * 4;
    const size_t MtB   = (size_t)C_ * C_ * 4;
    const size_t rtB   = (size_t)C_ * N_ * 4;
    const size_t fplB  = (size_t)1024 * C_ * 2;
    const size_t rtplB = (size_t)N_ * C_ * 2;
    const size_t xtB   = (size_t)N_ * C_ * 2;
    const size_t ttB   = (size_t)N_ * C_ * 2;
    const size_t vplB  = (size_t)C_ * N_ * 2;
    const size_t sB    = (size_t)N_ * N_ * 4;
    const size_t pB    = (size_t)N_ * N_ * 2;
    const size_t per_batch = 2 * xtB + 2 * ttB + 2 * vplB + sB + pB;
    const size_t persist   = posB + MtB + rtB + 2 * fplB + 2 * rtplB;

    size_t rem = (ws_size > persist) ? (ws_size - persist) : 0;
    int chunkB = (int)(rem / per_batch);
    if (chunkB < 1)  chunkB = 1;
    if (chunkB > B_) chunkB = B_;

    char* p = (char*)d_ws;
    float*    pos  = (float*)p;    p += posB;
    float*    Mtmp = (float*)p;    p += MtB;
    float*    rtmp = (float*)p;    p += rtB;
    ushort_t* Fh   = (ushort_t*)p; p += fplB;
    ushort_t* Fl   = (ushort_t*)p; p += fplB;
    ushort_t* rTh  = (ushort_t*)p; p += rtplB;
    ushort_t* rTl  = (ushort_t*)p; p += rtplB;
    ushort_t* xTh  = (ushort_t*)p; p += (size_t)chunkB * xtB;
    ushort_t* xTl  = (ushort_t*)p; p += (size_t)chunkB * xtB;
    ushort_t* tTh  = (ushort_t*)p; p += (size_t)chunkB * ttB;
    ushort_t* tTl  = (ushort_t*)p; p += (size_t)chunkB * ttB;
    ushort_t* vh   = (ushort_t*)p; p += (size_t)chunkB * vplB;
    ushort_t* vl   = (ushort_t*)p; p += (size_t)chunkB * vplB;
    float*    S    = (float*)p;    p += (size_t)chunkB * sB;
    ushort_t* P    = (ushort_t*)p; p += (size_t)chunkB * pB;

    dim3 blk16(16, 16);
    pos_kernel<<<(C_ * N_ + 255) / 256, 256, 0, stream>>>(rel_h, rel_w, pos);
    mmT_f32<<<dim3(C_ / 64, C_ / 64), blk16, 0, stream>>>(Wm, C_, Wm + (size_t)C_ * C_, C_,
                                                          Mtmp, C_, C_);
    mmT_f32<<<dim3(N_ / 64, C_ / 64), blk16, 0, stream>>>(Wm, C_, pos, N_, rtmp, N_, C_);
    f_split<<<(1024 * C_ + 255) / 256, 256, 0, stream>>>(Mtmp, Wm, Fh, Fl);
    xT_split<<<dim3(N_ / 32, C_ / 32, 1), 256, 0, stream>>>(rtmp, rTh, rTl);

    for (int b0 = 0; b0 < B_; b0 += chunkB) {
        int nb = (b0 + chunkB <= B_) ? chunkB : (B_ - b0);
        const float* x_b   = x   + (size_t)b0 * C_ * N_;
        float*       out_b = out + (size_t)b0 * C_ * N_;
        xT_split<<<dim3(N_ / 32, C_ / 32, nb), 256, 0, stream>>>(x_b, xTh, xTl);
        g1_mfma<<<dim3(4, 4, nb), 512, 0, stream>>>(Fh, Fl, xTh, xTl, tTh, tTl, vh, vl);
        g2_mfma<<<dim3(4, 4, nb), 512, 0, stream>>>(xTh, xTl, rTh, rTl, tTh, tTl, S);
        softmax_bf16<<<nb * N_, 256, 0, stream>>>(S, P);
        g4_mfma<<<dim3(4, 2, nb), 512, 0, stream>>>(vh, vl, P, out_b);
    }
}